// Round 8
// baseline (489.857 us; speedup 1.0000x reference)
//
#include <hip/hip_runtime.h>
#include <stdint.h>

#define DIN 128
#define D1 64
#define D2 32
#define MAXDEG 48  // P(deg>=48 | Poisson(16)) ~ 6e-11/node; guard drops overflow (never fires)

// ---------------- bf16 helpers (RTNE) ----------------
__device__ __forceinline__ unsigned short f2bf(float v) {
  unsigned u = __float_as_uint(v);
  unsigned r = u + 0x7fffu + ((u >> 16) & 1u);
  return (unsigned short)(r >> 16);
}
__device__ __forceinline__ float bf2f(unsigned short b) {
  return __uint_as_float(((unsigned)b) << 16);
}

// fp32 1/sqrt(deg+1); rsqrtf rel err ~1e-7 -> ~1e-5 absmax contribution (budget 9.3e-3)
__device__ __forceinline__ float dinv_of(int degv) {
  return rsqrtf((float)(degv + 1));
}

// ---------------- JAX Threefry-2x32/20 (key = (0,42)), partitionable ----------------
__device__ __forceinline__ unsigned rotl32(unsigned x, int r) {
  return (x << r) | (x >> (32 - r));
}

__device__ __forceinline__ unsigned threefry_fold(unsigned ctr) {
  unsigned k0 = 0u, k1 = 42u;
  unsigned ks0 = k0, ks1 = k1, ks2 = k0 ^ k1 ^ 0x1BD11BDAu;
  unsigned x0 = 0u, x1 = ctr;
  x0 += ks0; x1 += ks1;
#define TF_ROUND(r) { x0 += x1; x1 = rotl32(x1, (r)); x1 ^= x0; }
  TF_ROUND(13) TF_ROUND(15) TF_ROUND(26) TF_ROUND(6)
  x0 += ks1; x1 += ks2 + 1u;
  TF_ROUND(17) TF_ROUND(29) TF_ROUND(16) TF_ROUND(24)
  x0 += ks2; x1 += ks0 + 2u;
  TF_ROUND(13) TF_ROUND(15) TF_ROUND(26) TF_ROUND(6)
  x0 += ks0; x1 += ks1 + 3u;
  TF_ROUND(17) TF_ROUND(29) TF_ROUND(16) TF_ROUND(24)
  x0 += ks1; x1 += ks2 + 4u;
  TF_ROUND(13) TF_ROUND(15) TF_ROUND(26) TF_ROUND(6)
  x0 += ks2; x1 += ks0 + 5u;
#undef TF_ROUND
  return x0 ^ x1;  // partitionable threefry XOR-fold (verified R2)
}

__device__ __forceinline__ float dropout_scale(unsigned idx) {
  unsigned bits = threefry_fold(idx);
  float u = __uint_as_float((bits >> 9) | 0x3f800000u) - 1.0f;
  return (u < 0.8f) ? 1.25f : 0.0f;
}

// ============ K2: fused ELL build (blocks < G2) + gemm1 (blocks >= G2) ============
// gemm1 part writes UNSCALED bf16 h1p (deg is concurrently mutated by build part).
// LDS kept at 16.5 KB (K-chunked 4x32) so build blocks stay 8/CU.
__global__ __launch_bounds__(256) void build_gemm1_kernel(
    const int* __restrict__ src, const int* __restrict__ dst,
    int* __restrict__ deg, int* __restrict__ ell, int E, int G2,
    const float* __restrict__ x, const float* __restrict__ W1,
    unsigned short* __restrict__ h1p, int N) {
  __shared__ float xT[32][65];   // transposed x K-chunk, +1 pad
  __shared__ float Wl[32][D1];   // W1 K-chunk
  const int tid = threadIdx.x;

  if ((int)blockIdx.x < G2) {
    // ---- ELL build: 8 edges/thread, independent latency chains ----
    const int base = blockIdx.x * 2048 + tid;
    int e[8], d[8], s[8], r[8];
    bool v[8];
#pragma unroll
    for (int i = 0; i < 8; i++) { e[i] = base + 256 * i; v[i] = e[i] < E; }
#pragma unroll
    for (int i = 0; i < 8; i++) if (v[i]) { d[i] = dst[e[i]]; s[i] = src[e[i]]; }
#pragma unroll
    for (int i = 0; i < 8; i++) if (v[i]) r[i] = atomicAdd(&deg[d[i]], 1);
#pragma unroll
    for (int i = 0; i < 8; i++) if (v[i] && r[i] < MAXDEG) ell[d[i] * MAXDEG + r[i]] = s[i];
    return;
  }

  // ---- gemm1: 64x64 tile, K chunked 4x32 ----
  const int rowbase = ((int)blockIdx.x - G2) * 64;
  const int tx = tid & 15;
  const int ty = tid >> 4;
  float acc[4][4];
#pragma unroll
  for (int i = 0; i < 4; i++)
#pragma unroll
    for (int j = 0; j < 4; j++) acc[i][j] = 0.f;

  for (int c4 = 0; c4 < 4; c4++) {
    const int k0 = c4 * 32;
#pragma unroll
    for (int i = 0; i < 2; i++) {   // x chunk: 64 rows x 32 k = 512 float4
      int f = tid + 256 * i;
      int row = f >> 3;             // 8 float4 per row
      int kq = (f & 7) * 4;
      int gr = rowbase + row;
      float4 vv = make_float4(0.f, 0.f, 0.f, 0.f);
      if (gr < N) vv = *(const float4*)(x + (size_t)gr * DIN + k0 + kq);
      xT[kq + 0][row] = vv.x;
      xT[kq + 1][row] = vv.y;
      xT[kq + 2][row] = vv.z;
      xT[kq + 3][row] = vv.w;
    }
#pragma unroll
    for (int i = 0; i < 2; i++) {   // W1 chunk: 32 x 64 = 512 float4
      int f = tid + 256 * i;
      int k = f >> 4;               // 16 float4 per row
      int cc = (f & 15) * 4;
      *(float4*)&Wl[k][cc] = *(const float4*)(W1 + (size_t)(k0 + k) * D1 + cc);
    }
    __syncthreads();
#pragma unroll 4
    for (int k = 0; k < 32; k++) {
      float4 a = *(const float4*)&xT[k][4 * ty];
      float4 b = *(const float4*)&Wl[k][4 * tx];
      float av[4] = {a.x, a.y, a.z, a.w};
      float bv[4] = {b.x, b.y, b.z, b.w};
#pragma unroll
      for (int i = 0; i < 4; i++)
#pragma unroll
        for (int j = 0; j < 4; j++) acc[i][j] = fmaf(av[i], bv[j], acc[i][j]);
    }
    __syncthreads();
  }

#pragma unroll
  for (int i = 0; i < 4; i++) {   // epilogue: UNSCALED bf16
    int gr = rowbase + 4 * ty + i;
    if (gr < N) {
      ushort4 o;
      o.x = f2bf(acc[i][0]);
      o.y = f2bf(acc[i][1]);
      o.z = f2bf(acc[i][2]);
      o.w = f2bf(acc[i][3]);
      *(ushort4*)(h1p + (size_t)gr * D1 + 4 * tx) = o;
    }
  }
}

// ============ K3: fused agg1 (+bias+relu+dropout) -> LDS -> gemm2 ============
// Phase A: 128 nodes/block, one wave per node at a time; per-edge dinv[s] applied
// (h1p is unscaled). Result written TRANSPOSED to hT[f][r] (conflict-free (f+r)%32).
// Phase B: 128x32 gemm from LDS, epilogue pre-scales h2p rows by dinv (deg final).
__global__ __launch_bounds__(256) void agg1_gemm2_kernel(
    const int* __restrict__ deg, const int* __restrict__ ell,
    const unsigned short* __restrict__ h1p, const float* __restrict__ b1,
    const float* __restrict__ W2, unsigned short* __restrict__ h2p, int N) {
  __shared__ float hT[D1][129];   // [feat][row] +1 pad
  __shared__ float W2l[D1][D2];
  const int tid = threadIdx.x;
  const int nodebase = blockIdx.x * 128;

  // stage W2 (64x32 = 512 float4, 2/thread)
#pragma unroll
  for (int i = 0; i < 2; i++) {
    int f = tid + 256 * i;
    int k = f >> 3;
    int cc = (f & 7) * 4;
    *(float4*)&W2l[k][cc] = *(const float4*)(W2 + (size_t)k * D2 + cc);
  }

  // ---- phase A ----
  const int w = tid >> 6;       // wave 0..3 handles rows [32w, 32w+32)
  const int f = tid & 63;
  const float bias = b1[f];
  for (int i = 0; i < 32; i++) {
    int r = w * 32 + i;
    int d = nodebase + r;
    if (d >= N) break;          // wave-uniform
    int dg = deg[d];
    int cnt = min(dg, MAXDEG);
    int base = d * MAXDEG;
    float dd = dinv_of(dg);
    float acc = bf2f(h1p[(size_t)d * D1 + f]) * dd;  // self-loop
    int j = 0;
    for (; j + 7 < cnt; j += 8) {
      int s[8];
#pragma unroll
      for (int q = 0; q < 8; q++) s[q] = ell[base + j + q];
      unsigned short a[8];
      int sd[8];
#pragma unroll
      for (int q = 0; q < 8; q++) a[q] = h1p[(size_t)s[q] * D1 + f];
#pragma unroll
      for (int q = 0; q < 8; q++) sd[q] = deg[s[q]];
#pragma unroll
      for (int q = 0; q < 8; q++) acc = fmaf(bf2f(a[q]), dinv_of(sd[q]), acc);
    }
    for (; j < cnt; ++j) {
      int s0 = ell[base + j];
      acc = fmaf(bf2f(h1p[(size_t)s0 * D1 + f]), dinv_of(deg[s0]), acc);
    }
    float v = fmaf(dd, acc, bias);
    v = fmaxf(v, 0.0f);
    v *= dropout_scale((unsigned)(d * D1 + f));
    hT[f][r] = v;
  }
  __syncthreads();

  // ---- phase B: 128x32 gemm from LDS ----
  const int tx = tid & 7;
  const int ty = tid >> 3;
  float acc2[4][4];
#pragma unroll
  for (int i = 0; i < 4; i++)
#pragma unroll
    for (int j = 0; j < 4; j++) acc2[i][j] = 0.f;

#pragma unroll 4
  for (int k = 0; k < D1; k++) {
    float4 a = *(const float4*)&hT[k][4 * ty];
    float4 b = *(const float4*)&W2l[k][4 * tx];
    float av[4] = {a.x, a.y, a.z, a.w};
    float bv[4] = {b.x, b.y, b.z, b.w};
#pragma unroll
    for (int i = 0; i < 4; i++)
#pragma unroll
      for (int j = 0; j < 4; j++) acc2[i][j] = fmaf(av[i], bv[j], acc2[i][j]);
  }

#pragma unroll
  for (int i = 0; i < 4; i++) {
    int gr = nodebase + 4 * ty + i;
    if (gr < N) {
      float di = dinv_of(deg[gr]);   // deg final here -> prescale h2p
      ushort4 o;
      o.x = f2bf(acc2[i][0] * di);
      o.y = f2bf(acc2[i][1] * di);
      o.z = f2bf(acc2[i][2] * di);
      o.w = f2bf(acc2[i][3] * di);
      *(ushort4*)(h2p + (size_t)gr * D2 + 4 * tx) = o;
    }
  }
}

// ============ K4: agg2 (ELL bf16 gather, 2 half-waves) + bias ============
__global__ __launch_bounds__(256) void agg2_kernel(const int* __restrict__ deg,
                                                   const int* __restrict__ ell,
                                                   const unsigned short* __restrict__ h2p,
                                                   const float* __restrict__ b2,
                                                   float* __restrict__ out, int N) {
  const int wslot = __builtin_amdgcn_readfirstlane(threadIdx.x >> 6);
  const int d = blockIdx.x * 4 + wslot;
  const int lane = threadIdx.x & 63;
  const int f = lane & 31;
  const int h = lane >> 5;
  const int dg = deg[d];
  const int cnt = min(dg, MAXDEG);
  const int base = d * MAXDEG;
  float acc = (h == 0) ? bf2f(h2p[(size_t)d * D2 + f]) : 0.0f;  // self-loop once
  int j = h;
  for (; j + 6 < cnt; j += 8) {  // this half handles j, j+2, j+4, j+6
    int s0 = ell[base + j], s1 = ell[base + j + 2];
    int s2 = ell[base + j + 4], s3 = ell[base + j + 6];
    unsigned short a0 = h2p[(size_t)s0 * D2 + f];
    unsigned short a1 = h2p[(size_t)s1 * D2 + f];
    unsigned short a2 = h2p[(size_t)s2 * D2 + f];
    unsigned short a3 = h2p[(size_t)s3 * D2 + f];
    acc += bf2f(a0); acc += bf2f(a1); acc += bf2f(a2); acc += bf2f(a3);
  }
  for (; j < cnt; j += 2) acc += bf2f(h2p[(size_t)ell[base + j] * D2 + f]);
  acc += __shfl_down(acc, 32, 64);  // fold upper half into lower
  if (h == 0) {
    out[(size_t)d * D2 + f] = fmaf(dinv_of(dg), acc, b2[f]);
  }
}

extern "C" void kernel_launch(void* const* d_in, const int* in_sizes, int n_in,
                              void* d_out, int out_size, void* d_ws, size_t ws_size,
                              hipStream_t stream) {
  const float* x  = (const float*)d_in[0];
  const int*   ei = (const int*)d_in[1];
  const float* W1 = (const float*)d_in[2];
  const float* b1 = (const float*)d_in[3];
  const float* W2 = (const float*)d_in[4];
  const float* b2 = (const float*)d_in[5];
  const int N = in_sizes[0] / DIN;   // 100000
  const int E = in_sizes[1] / 2;     // 1600000
  const int* src = ei;
  const int* dst = ei + E;
  float* out = (float*)d_out;

  char* ws = (char*)d_ws;
  size_t off = 0;
  auto alloc = [&](size_t bytes) -> char* {
    char* p = ws + off;
    off += (bytes + 255) / 256 * 256;
    return p;
  };
  unsigned short* h1p = (unsigned short*)alloc((size_t)N * D1 * 2);  // bf16 unscaled
  unsigned short* h2p = (unsigned short*)alloc((size_t)N * D2 * 2);  // bf16 prescaled
  int*            ell = (int*)alloc((size_t)N * MAXDEG * 4);
  int*            deg = (int*)alloc((size_t)N * 4);
  (void)ws_size; (void)n_in; (void)out_size;

  hipMemsetAsync(deg, 0, (size_t)N * 4, stream);

  const int G2 = (E + 2047) / 2048;        // build blocks (8 edges/thread)
  const int G1 = (N + 63) / 64;            // gemm1 blocks
  build_gemm1_kernel<<<G2 + G1, 256, 0, stream>>>(src, dst, deg, ell, E, G2,
                                                  x, W1, h1p, N);
  agg1_gemm2_kernel<<<(N + 127) / 128, 256, 0, stream>>>(deg, ell, h1p, b1, W2, h2p, N);
  agg2_kernel<<<N / 4, 256, 0, stream>>>(deg, ell, h2p, b2, out, N);
}

// Round 9
// 328.192 us; speedup vs baseline: 1.4926x; 1.4926x over previous
//
#include <hip/hip_runtime.h>
#include <stdint.h>

#define DIN 128
#define D1 64
#define D2 32
#define MAXDEG 48  // P(deg>=48 | Poisson(16)) ~ 6e-11/node; guard drops overflow (never fires)

// ---------------- bf16 helpers (RTNE) ----------------
__device__ __forceinline__ unsigned short f2bf(float v) {
  unsigned u = __float_as_uint(v);
  unsigned r = u + 0x7fffu + ((u >> 16) & 1u);
  return (unsigned short)(r >> 16);
}
__device__ __forceinline__ float bf2f(unsigned short b) {
  return __uint_as_float(((unsigned)b) << 16);
}

// correctly-rounded fp32 1/sqrt(deg+1) via double (matches np reference)
__device__ __forceinline__ float node_dinv(const int* __restrict__ deg, int n) {
  return (float)(1.0 / sqrt((double)(deg[n] + 1)));
}

// ---------------- JAX Threefry-2x32/20 (key = (0,42)), partitionable ----------------
__device__ __forceinline__ unsigned rotl32(unsigned x, int r) {
  return (x << r) | (x >> (32 - r));
}

__device__ __forceinline__ unsigned threefry_fold(unsigned ctr) {
  unsigned k0 = 0u, k1 = 42u;
  unsigned ks0 = k0, ks1 = k1, ks2 = k0 ^ k1 ^ 0x1BD11BDAu;
  unsigned x0 = 0u, x1 = ctr;
  x0 += ks0; x1 += ks1;
#define TF_ROUND(r) { x0 += x1; x1 = rotl32(x1, (r)); x1 ^= x0; }
  TF_ROUND(13) TF_ROUND(15) TF_ROUND(26) TF_ROUND(6)
  x0 += ks1; x1 += ks2 + 1u;
  TF_ROUND(17) TF_ROUND(29) TF_ROUND(16) TF_ROUND(24)
  x0 += ks2; x1 += ks0 + 2u;
  TF_ROUND(13) TF_ROUND(15) TF_ROUND(26) TF_ROUND(6)
  x0 += ks0; x1 += ks1 + 3u;
  TF_ROUND(17) TF_ROUND(29) TF_ROUND(16) TF_ROUND(24)
  x0 += ks1; x1 += ks2 + 4u;
  TF_ROUND(13) TF_ROUND(15) TF_ROUND(26) TF_ROUND(6)
  x0 += ks2; x1 += ks0 + 5u;
#undef TF_ROUND
  return x0 ^ x1;  // partitionable threefry XOR-fold (verified R2)
}

__device__ __forceinline__ float dropout_scale(unsigned idx) {
  unsigned bits = threefry_fold(idx);
  float u = __uint_as_float((bits >> 9) | 0x3f800000u) - 1.0f;
  return (u < 0.8f) ? 1.25f : 0.0f;
}

// ---------------- fused histogram + ELL scatter (8 edges/thread) ----------------
// NOTE (R8 lesson): keep this random-RMW storm in its OWN dispatch — fusing it
// with streaming GEMM dragged all traffic to the ~1 TB/s random-write ceiling.
__global__ __launch_bounds__(256) void build_ell_kernel(const int* __restrict__ src,
                                                        const int* __restrict__ dst,
                                                        int* __restrict__ deg,
                                                        int* __restrict__ ell, int E) {
  const int base = blockIdx.x * 2048 + threadIdx.x;
  int e[8], d[8], s[8], r[8];
  bool v[8];
#pragma unroll
  for (int i = 0; i < 8; i++) { e[i] = base + 256 * i; v[i] = e[i] < E; }
#pragma unroll
  for (int i = 0; i < 8; i++) if (v[i]) { d[i] = dst[e[i]]; s[i] = src[e[i]]; }
#pragma unroll
  for (int i = 0; i < 8; i++) if (v[i]) r[i] = atomicAdd(&deg[d[i]], 1);
#pragma unroll
  for (int i = 0; i < 8; i++) if (v[i] && r[i] < MAXDEG) ell[d[i] * MAXDEG + r[i]] = s[i];
}

// ---------------- GEMM1: h1p(bf16) = (x @ W1) * dinv, 64x64 tile, K chunked 4x32 ----------------
// 16.5 KB LDS -> 8 blocks/CU (vs 66 KB -> 2) for latency hiding on the x stream.
__global__ __launch_bounds__(256) void gemm1_kernel(const float* __restrict__ x,
                                                    const float* __restrict__ W1,
                                                    const int* __restrict__ deg,
                                                    unsigned short* __restrict__ h1p, int N) {
  __shared__ float xT[32][65];   // transposed x K-chunk, +1 pad
  __shared__ float Wl[32][D1];   // W1 K-chunk
  const int tid = threadIdx.x;
  const int rowbase = blockIdx.x * 64;
  const int tx = tid & 15;
  const int ty = tid >> 4;
  float acc[4][4];
#pragma unroll
  for (int i = 0; i < 4; i++)
#pragma unroll
    for (int j = 0; j < 4; j++) acc[i][j] = 0.f;

  for (int c4 = 0; c4 < 4; c4++) {
    const int k0 = c4 * 32;
#pragma unroll
    for (int i = 0; i < 2; i++) {   // x chunk: 64 rows x 32 k = 512 float4
      int f = tid + 256 * i;
      int row = f >> 3;             // 8 float4 per row
      int kq = (f & 7) * 4;
      int gr = rowbase + row;
      float4 vv = make_float4(0.f, 0.f, 0.f, 0.f);
      if (gr < N) vv = *(const float4*)(x + (size_t)gr * DIN + k0 + kq);
      xT[kq + 0][row] = vv.x;
      xT[kq + 1][row] = vv.y;
      xT[kq + 2][row] = vv.z;
      xT[kq + 3][row] = vv.w;
    }
#pragma unroll
    for (int i = 0; i < 2; i++) {   // W1 chunk: 32 x 64 = 512 float4
      int f = tid + 256 * i;
      int k = f >> 4;               // 16 float4 per row
      int cc = (f & 15) * 4;
      *(float4*)&Wl[k][cc] = *(const float4*)(W1 + (size_t)(k0 + k) * D1 + cc);
    }
    __syncthreads();
#pragma unroll 4
    for (int k = 0; k < 32; k++) {
      float4 a = *(const float4*)&xT[k][4 * ty];
      float4 b = *(const float4*)&Wl[k][4 * tx];
      float av[4] = {a.x, a.y, a.z, a.w};
      float bv[4] = {b.x, b.y, b.z, b.w};
#pragma unroll
      for (int i = 0; i < 4; i++)
#pragma unroll
        for (int j = 0; j < 4; j++) acc[i][j] = fmaf(av[i], bv[j], acc[i][j]);
    }
    __syncthreads();
  }

#pragma unroll
  for (int i = 0; i < 4; i++) {   // epilogue: prescale by dinv (deg is final)
    int gr = rowbase + 4 * ty + i;
    if (gr < N) {
      float di = node_dinv(deg, gr);
      ushort4 o;
      o.x = f2bf(acc[i][0] * di);
      o.y = f2bf(acc[i][1] * di);
      o.z = f2bf(acc[i][2] * di);
      o.w = f2bf(acc[i][3] * di);
      *(ushort4*)(h1p + (size_t)gr * D1 + 4 * tx) = o;
    }
  }
}

// ---------------- agg1 (ELL bf16 gather, one wave/node, unroll 8) + bias + relu + dropout ----------------
__global__ __launch_bounds__(256) void agg1_kernel(const int* __restrict__ deg,
                                                   const int* __restrict__ ell,
                                                   const unsigned short* __restrict__ h1p,
                                                   const float* __restrict__ b1,
                                                   float* __restrict__ h1d, int N) {
  const int wslot = __builtin_amdgcn_readfirstlane(threadIdx.x >> 6);
  const int d = blockIdx.x * 4 + wslot;  // N % 4 == 0
  const int f = threadIdx.x & 63;
  const int cnt = min(deg[d], MAXDEG);
  const int base = d * MAXDEG;
  float acc = bf2f(h1p[(size_t)d * D1 + f]);  // self-loop (dinv[d]-scaled)
  int j = 0;
  for (; j + 7 < cnt; j += 8) {
    int s[8];
#pragma unroll
    for (int i = 0; i < 8; i++) s[i] = ell[base + j + i];
    unsigned short a[8];
#pragma unroll
    for (int i = 0; i < 8; i++) a[i] = h1p[(size_t)s[i] * D1 + f];
#pragma unroll
    for (int i = 0; i < 8; i++) acc += bf2f(a[i]);
  }
  for (; j < cnt; ++j) acc += bf2f(h1p[(size_t)ell[base + j] * D1 + f]);
  float di = node_dinv(deg, d);
  float v = fmaf(di, acc, b1[f]);
  v = fmaxf(v, 0.0f);
  v *= dropout_scale((unsigned)(d * D1 + f));
  h1d[(size_t)d * D1 + f] = v;
}

// ---------------- GEMM2 (LDS-tiled): h2p(bf16) = (h1d @ W2) * dinv, 128x32 tile ----------------
__global__ __launch_bounds__(256) void gemm2_kernel(const float* __restrict__ h1d,
                                                    const float* __restrict__ W2,
                                                    const int* __restrict__ deg,
                                                    unsigned short* __restrict__ h2p, int N) {
  __shared__ float hT[D1][129];
  __shared__ float Wl[D1][D2];
  const int tid = threadIdx.x;
  const int rowbase = blockIdx.x * 128;

#pragma unroll
  for (int i = 0; i < 8; i++) {
    int f = tid + 256 * i;
    int row = f >> 4;
    int kq = (f & 15) * 4;
    int gr = rowbase + row;
    float4 v = make_float4(0.f, 0.f, 0.f, 0.f);
    if (gr < N) v = *(const float4*)(h1d + (size_t)gr * D1 + kq);
    hT[kq + 0][row] = v.x;
    hT[kq + 1][row] = v.y;
    hT[kq + 2][row] = v.z;
    hT[kq + 3][row] = v.w;
  }
#pragma unroll
  for (int i = 0; i < 2; i++) {
    int f = tid + 256 * i;
    int k = f >> 3;
    int c = (f & 7) * 4;
    *(float4*)&Wl[k][c] = *(const float4*)(W2 + (size_t)k * D2 + c);
  }
  __syncthreads();

  const int tx = tid & 7;
  const int ty = tid >> 3;
  float acc[4][4];
#pragma unroll
  for (int i = 0; i < 4; i++)
#pragma unroll
    for (int j = 0; j < 4; j++) acc[i][j] = 0.f;

#pragma unroll 4
  for (int k = 0; k < D1; k++) {
    float4 a = *(const float4*)&hT[k][4 * ty];
    float4 b = *(const float4*)&Wl[k][4 * tx];
    float av[4] = {a.x, a.y, a.z, a.w};
    float bv[4] = {b.x, b.y, b.z, b.w};
#pragma unroll
    for (int i = 0; i < 4; i++)
#pragma unroll
      for (int j = 0; j < 4; j++) acc[i][j] = fmaf(av[i], bv[j], acc[i][j]);
  }

#pragma unroll
  for (int i = 0; i < 4; i++) {
    int gr = rowbase + 4 * ty + i;
    if (gr < N) {
      float di = node_dinv(deg, gr);
      ushort4 o;
      o.x = f2bf(acc[i][0] * di);
      o.y = f2bf(acc[i][1] * di);
      o.z = f2bf(acc[i][2] * di);
      o.w = f2bf(acc[i][3] * di);
      *(ushort4*)(h2p + (size_t)gr * D2 + 4 * tx) = o;
    }
  }
}

// ---------------- agg2 (ELL bf16 gather, 2 half-waves) + bias ----------------
__global__ __launch_bounds__(256) void agg2_kernel(const int* __restrict__ deg,
                                                   const int* __restrict__ ell,
                                                   const unsigned short* __restrict__ h2p,
                                                   const float* __restrict__ b2,
                                                   float* __restrict__ out, int N) {
  const int wslot = __builtin_amdgcn_readfirstlane(threadIdx.x >> 6);
  const int d = blockIdx.x * 4 + wslot;
  const int lane = threadIdx.x & 63;
  const int f = lane & 31;
  const int h = lane >> 5;
  const int cnt = min(deg[d], MAXDEG);
  const int base = d * MAXDEG;
  float acc = (h == 0) ? bf2f(h2p[(size_t)d * D2 + f]) : 0.0f;  // self-loop once
  int j = h;
  for (; j + 6 < cnt; j += 8) {  // this half handles j, j+2, j+4, j+6
    int s0 = ell[base + j], s1 = ell[base + j + 2];
    int s2 = ell[base + j + 4], s3 = ell[base + j + 6];
    unsigned short a0 = h2p[(size_t)s0 * D2 + f];
    unsigned short a1 = h2p[(size_t)s1 * D2 + f];
    unsigned short a2 = h2p[(size_t)s2 * D2 + f];
    unsigned short a3 = h2p[(size_t)s3 * D2 + f];
    acc += bf2f(a0); acc += bf2f(a1); acc += bf2f(a2); acc += bf2f(a3);
  }
  for (; j < cnt; j += 2) acc += bf2f(h2p[(size_t)ell[base + j] * D2 + f]);
  acc += __shfl_down(acc, 32, 64);  // fold upper half into lower
  if (h == 0) {
    out[(size_t)d * D2 + f] = fmaf(node_dinv(deg, d), acc, b2[f]);
  }
}

extern "C" void kernel_launch(void* const* d_in, const int* in_sizes, int n_in,
                              void* d_out, int out_size, void* d_ws, size_t ws_size,
                              hipStream_t stream) {
  const float* x  = (const float*)d_in[0];
  const int*   ei = (const int*)d_in[1];
  const float* W1 = (const float*)d_in[2];
  const float* b1 = (const float*)d_in[3];
  const float* W2 = (const float*)d_in[4];
  const float* b2 = (const float*)d_in[5];
  const int N = in_sizes[0] / DIN;   // 100000
  const int E = in_sizes[1] / 2;     // 1600000
  const int* src = ei;
  const int* dst = ei + E;
  float* out = (float*)d_out;

  char* ws = (char*)d_ws;
  size_t off = 0;
  auto alloc = [&](size_t bytes) -> char* {
    char* p = ws + off;
    off += (bytes + 255) / 256 * 256;
    return p;
  };
  unsigned short* h1p = (unsigned short*)alloc((size_t)N * D1 * 2);  // bf16; h2p aliases
  float*          h1d = (float*)alloc((size_t)N * D1 * 4);           // fp32
  int*            ell = (int*)alloc((size_t)N * MAXDEG * 4);
  int*            deg = (int*)alloc((size_t)N * 4);
  unsigned short* h2p = h1p;  // alias: h1p dead after agg1, gemm2 writes after
  (void)ws_size; (void)n_in; (void)out_size;

  hipMemsetAsync(deg, 0, (size_t)N * 4, stream);

  build_ell_kernel<<<(E + 2047) / 2048, 256, 0, stream>>>(src, dst, deg, ell, E);
  gemm1_kernel<<<(N + 63) / 64, 256, 0, stream>>>(x, W1, deg, h1p, N);
  agg1_kernel<<<N / 4, 256, 0, stream>>>(deg, ell, h1p, b1, h1d, N);
  gemm2_kernel<<<(N + 127) / 128, 256, 0, stream>>>(h1d, W2, deg, h2p, N);
  agg2_kernel<<<N / 4, 256, 0, stream>>>(deg, ell, h2p, b2, out, N);
}

// Round 10
// 289.890 us; speedup vs baseline: 1.6898x; 1.1321x over previous
//
#include <hip/hip_runtime.h>
#include <stdint.h>

#define DIN 128
#define D1 64
#define D2 32
#define MAXDEG 48   // P(deg>=48 | Poisson(16)) ~ 6e-11/node; guard drops overflow (never fires)
#define BCAP 4608   // bucket capacity: Poisson(4096) + 8 sigma
#define CBLK 8192   // edges per bin-pass block

// ---------------- bf16 helpers (RTNE) ----------------
__device__ __forceinline__ unsigned short f2bf(float v) {
  unsigned u = __float_as_uint(v);
  unsigned r = u + 0x7fffu + ((u >> 16) & 1u);
  return (unsigned short)(r >> 16);
}
__device__ __forceinline__ float bf2f(unsigned short b) {
  return __uint_as_float(((unsigned)b) << 16);
}

// correctly-rounded fp32 1/sqrt(deg+1) via double (matches np reference)
__device__ __forceinline__ float node_dinv(const int* __restrict__ deg, int n) {
  return (float)(1.0 / sqrt((double)(deg[n] + 1)));
}

// ---------------- JAX Threefry-2x32/20 (key = (0,42)), partitionable ----------------
__device__ __forceinline__ unsigned rotl32(unsigned x, int r) {
  return (x << r) | (x >> (32 - r));
}

__device__ __forceinline__ unsigned threefry_fold(unsigned ctr) {
  unsigned k0 = 0u, k1 = 42u;
  unsigned ks0 = k0, ks1 = k1, ks2 = k0 ^ k1 ^ 0x1BD11BDAu;
  unsigned x0 = 0u, x1 = ctr;
  x0 += ks0; x1 += ks1;
#define TF_ROUND(r) { x0 += x1; x1 = rotl32(x1, (r)); x1 ^= x0; }
  TF_ROUND(13) TF_ROUND(15) TF_ROUND(26) TF_ROUND(6)
  x0 += ks1; x1 += ks2 + 1u;
  TF_ROUND(17) TF_ROUND(29) TF_ROUND(16) TF_ROUND(24)
  x0 += ks2; x1 += ks0 + 2u;
  TF_ROUND(13) TF_ROUND(15) TF_ROUND(26) TF_ROUND(6)
  x0 += ks0; x1 += ks1 + 3u;
  TF_ROUND(17) TF_ROUND(29) TF_ROUND(16) TF_ROUND(24)
  x0 += ks1; x1 += ks2 + 4u;
  TF_ROUND(13) TF_ROUND(15) TF_ROUND(26) TF_ROUND(6)
  x0 += ks2; x1 += ks0 + 5u;
#undef TF_ROUND
  return x0 ^ x1;  // partitionable threefry XOR-fold (verified R2)
}

__device__ __forceinline__ float dropout_scale(unsigned idx) {
  unsigned bits = threefry_fold(idx);
  float u = __uint_as_float((bits >> 9) | 0x3f800000u) - 1.0f;
  return (u < 0.8f) ? 1.25f : 0.0f;
}

// ============ Pass C: bin edges into 256-node buckets (coalesced chunk writes) ============
// bucket = dst >> 8. Per-block LDS histogram -> one global atomicAdd per (block,bucket)
// chunk reservation -> packed (dst,src) pairs written contiguously.
__global__ __launch_bounds__(256) void bin_kernel(const int* __restrict__ src,
                                                  const int* __restrict__ dst,
                                                  int* __restrict__ cursor,
                                                  uint2* __restrict__ binned,
                                                  int E, int NBK) {
  __shared__ int cnt[512];
  __shared__ int cbase[512];
  const int tid = threadIdx.x;
  const int e0 = blockIdx.x * CBLK;

  for (int b = tid; b < NBK; b += 256) cnt[b] = 0;
  __syncthreads();

  // phase 1: count
#pragma unroll 4
  for (int i = 0; i < CBLK / 256; i++) {
    int e = e0 + tid + 256 * i;
    if (e < E) atomicAdd(&cnt[dst[e] >> 8], 1);
  }
  __syncthreads();

  // phase 2: reserve contiguous chunks
  for (int b = tid; b < NBK; b += 256) {
    int c = cnt[b];
    if (c > 0) cbase[b] = b * BCAP + atomicAdd(&cursor[b], c);
    cnt[b] = 0;
  }
  __syncthreads();

  // phase 3: write pairs into chunks (contiguous per bucket per block)
#pragma unroll 4
  for (int i = 0; i < CBLK / 256; i++) {
    int e = e0 + tid + 256 * i;
    if (e < E) {
      int d = dst[e];
      int b = d >> 8;
      int rk = atomicAdd(&cnt[b], 1);
      int pos = cbase[b] + rk;
      if (pos - b * BCAP < BCAP)  // statistically never false
        binned[pos] = make_uint2((unsigned)d, (unsigned)src[e]);
    }
  }
}

// ============ Pass D: build ELL + deg from one bucket per block (LDS ranks) ============
// ELL window per block = 256 nodes x 192 B = 49 KB, single XCD -> write-back coalesces.
__global__ __launch_bounds__(256) void ellbuild_kernel(const uint2* __restrict__ binned,
                                                       const int* __restrict__ cursor,
                                                       int* __restrict__ deg,
                                                       int* __restrict__ ell, int N) {
  __shared__ int r[256];
  const int tid = threadIdx.x;
  const int b = blockIdx.x;
  const int nodebase = b << 8;
  r[tid] = 0;
  __syncthreads();

  int cnt = cursor[b];
  if (cnt > BCAP) cnt = BCAP;
  const uint2* seg = binned + (size_t)b * BCAP;
  for (int i = tid; i < cnt; i += 256) {
    uint2 p = seg[i];
    int local = (int)p.x - nodebase;
    int rk = atomicAdd(&r[local], 1);
    if (rk < MAXDEG) ell[(int)p.x * MAXDEG + rk] = (int)p.y;
  }
  __syncthreads();

  int node = nodebase + tid;
  if (node < N) deg[node] = r[tid];
}

// ---------------- GEMM1: h1p(bf16) = (x @ W1) * dinv, 64x64 tile, K chunked 4x32 ----------------
__global__ __launch_bounds__(256) void gemm1_kernel(const float* __restrict__ x,
                                                    const float* __restrict__ W1,
                                                    const int* __restrict__ deg,
                                                    unsigned short* __restrict__ h1p, int N) {
  __shared__ float xT[32][65];   // transposed x K-chunk, +1 pad
  __shared__ float Wl[32][D1];   // W1 K-chunk
  const int tid = threadIdx.x;
  const int rowbase = blockIdx.x * 64;
  const int tx = tid & 15;
  const int ty = tid >> 4;
  float acc[4][4];
#pragma unroll
  for (int i = 0; i < 4; i++)
#pragma unroll
    for (int j = 0; j < 4; j++) acc[i][j] = 0.f;

  for (int c4 = 0; c4 < 4; c4++) {
    const int k0 = c4 * 32;
#pragma unroll
    for (int i = 0; i < 2; i++) {   // x chunk: 64 rows x 32 k = 512 float4
      int f = tid + 256 * i;
      int row = f >> 3;             // 8 float4 per row
      int kq = (f & 7) * 4;
      int gr = rowbase + row;
      float4 vv = make_float4(0.f, 0.f, 0.f, 0.f);
      if (gr < N) vv = *(const float4*)(x + (size_t)gr * DIN + k0 + kq);
      xT[kq + 0][row] = vv.x;
      xT[kq + 1][row] = vv.y;
      xT[kq + 2][row] = vv.z;
      xT[kq + 3][row] = vv.w;
    }
#pragma unroll
    for (int i = 0; i < 2; i++) {   // W1 chunk: 32 x 64 = 512 float4
      int f = tid + 256 * i;
      int k = f >> 4;               // 16 float4 per row
      int cc = (f & 15) * 4;
      *(float4*)&Wl[k][cc] = *(const float4*)(W1 + (size_t)(k0 + k) * D1 + cc);
    }
    __syncthreads();
#pragma unroll 4
    for (int k = 0; k < 32; k++) {
      float4 a = *(const float4*)&xT[k][4 * ty];
      float4 b = *(const float4*)&Wl[k][4 * tx];
      float av[4] = {a.x, a.y, a.z, a.w};
      float bv[4] = {b.x, b.y, b.z, b.w};
#pragma unroll
      for (int i = 0; i < 4; i++)
#pragma unroll
        for (int j = 0; j < 4; j++) acc[i][j] = fmaf(av[i], bv[j], acc[i][j]);
    }
    __syncthreads();
  }

#pragma unroll
  for (int i = 0; i < 4; i++) {   // epilogue: prescale by dinv (deg final)
    int gr = rowbase + 4 * ty + i;
    if (gr < N) {
      float di = node_dinv(deg, gr);
      ushort4 o;
      o.x = f2bf(acc[i][0] * di);
      o.y = f2bf(acc[i][1] * di);
      o.z = f2bf(acc[i][2] * di);
      o.w = f2bf(acc[i][3] * di);
      *(ushort4*)(h1p + (size_t)gr * D1 + 4 * tx) = o;
    }
  }
}

// ---------------- agg1 (ELL bf16 gather, one wave/node, unroll 8) + bias + relu + dropout ----------------
__global__ __launch_bounds__(256) void agg1_kernel(const int* __restrict__ deg,
                                                   const int* __restrict__ ell,
                                                   const unsigned short* __restrict__ h1p,
                                                   const float* __restrict__ b1,
                                                   float* __restrict__ h1d, int N) {
  const int wslot = __builtin_amdgcn_readfirstlane(threadIdx.x >> 6);
  const int d = blockIdx.x * 4 + wslot;  // N % 4 == 0
  const int f = threadIdx.x & 63;
  const int cnt = min(deg[d], MAXDEG);
  const int base = d * MAXDEG;
  float acc = bf2f(h1p[(size_t)d * D1 + f]);  // self-loop (dinv[d]-scaled)
  int j = 0;
  for (; j + 7 < cnt; j += 8) {
    int s[8];
#pragma unroll
    for (int i = 0; i < 8; i++) s[i] = ell[base + j + i];
    unsigned short a[8];
#pragma unroll
    for (int i = 0; i < 8; i++) a[i] = h1p[(size_t)s[i] * D1 + f];
#pragma unroll
    for (int i = 0; i < 8; i++) acc += bf2f(a[i]);
  }
  for (; j < cnt; ++j) acc += bf2f(h1p[(size_t)ell[base + j] * D1 + f]);
  float di = node_dinv(deg, d);
  float v = fmaf(di, acc, b1[f]);
  v = fmaxf(v, 0.0f);
  v *= dropout_scale((unsigned)(d * D1 + f));
  h1d[(size_t)d * D1 + f] = v;
}

// ---------------- GEMM2 (LDS-tiled): h2p(bf16) = (h1d @ W2) * dinv, 128x32 tile ----------------
__global__ __launch_bounds__(256) void gemm2_kernel(const float* __restrict__ h1d,
                                                    const float* __restrict__ W2,
                                                    const int* __restrict__ deg,
                                                    unsigned short* __restrict__ h2p, int N) {
  __shared__ float hT[D1][129];
  __shared__ float Wl[D1][D2];
  const int tid = threadIdx.x;
  const int rowbase = blockIdx.x * 128;

#pragma unroll
  for (int i = 0; i < 8; i++) {
    int f = tid + 256 * i;
    int row = f >> 4;
    int kq = (f & 15) * 4;
    int gr = rowbase + row;
    float4 v = make_float4(0.f, 0.f, 0.f, 0.f);
    if (gr < N) v = *(const float4*)(h1d + (size_t)gr * D1 + kq);
    hT[kq + 0][row] = v.x;
    hT[kq + 1][row] = v.y;
    hT[kq + 2][row] = v.z;
    hT[kq + 3][row] = v.w;
  }
#pragma unroll
  for (int i = 0; i < 2; i++) {
    int f = tid + 256 * i;
    int k = f >> 3;
    int c = (f & 7) * 4;
    *(float4*)&Wl[k][c] = *(const float4*)(W2 + (size_t)k * D2 + c);
  }
  __syncthreads();

  const int tx = tid & 7;
  const int ty = tid >> 3;
  float acc[4][4];
#pragma unroll
  for (int i = 0; i < 4; i++)
#pragma unroll
    for (int j = 0; j < 4; j++) acc[i][j] = 0.f;

#pragma unroll 4
  for (int k = 0; k < D1; k++) {
    float4 a = *(const float4*)&hT[k][4 * ty];
    float4 b = *(const float4*)&Wl[k][4 * tx];
    float av[4] = {a.x, a.y, a.z, a.w};
    float bv[4] = {b.x, b.y, b.z, b.w};
#pragma unroll
    for (int i = 0; i < 4; i++)
#pragma unroll
      for (int j = 0; j < 4; j++) acc[i][j] = fmaf(av[i], bv[j], acc[i][j]);
  }

#pragma unroll
  for (int i = 0; i < 4; i++) {
    int gr = rowbase + 4 * ty + i;
    if (gr < N) {
      float di = node_dinv(deg, gr);
      ushort4 o;
      o.x = f2bf(acc[i][0] * di);
      o.y = f2bf(acc[i][1] * di);
      o.z = f2bf(acc[i][2] * di);
      o.w = f2bf(acc[i][3] * di);
      *(ushort4*)(h2p + (size_t)gr * D2 + 4 * tx) = o;
    }
  }
}

// ---------------- agg2 (ELL bf16 gather, 2 half-waves) + bias ----------------
__global__ __launch_bounds__(256) void agg2_kernel(const int* __restrict__ deg,
                                                   const int* __restrict__ ell,
                                                   const unsigned short* __restrict__ h2p,
                                                   const float* __restrict__ b2,
                                                   float* __restrict__ out, int N) {
  const int wslot = __builtin_amdgcn_readfirstlane(threadIdx.x >> 6);
  const int d = blockIdx.x * 4 + wslot;
  const int lane = threadIdx.x & 63;
  const int f = lane & 31;
  const int h = lane >> 5;
  const int cnt = min(deg[d], MAXDEG);
  const int base = d * MAXDEG;
  float acc = (h == 0) ? bf2f(h2p[(size_t)d * D2 + f]) : 0.0f;  // self-loop once
  int j = h;
  for (; j + 6 < cnt; j += 8) {  // this half handles j, j+2, j+4, j+6
    int s0 = ell[base + j], s1 = ell[base + j + 2];
    int s2 = ell[base + j + 4], s3 = ell[base + j + 6];
    unsigned short a0 = h2p[(size_t)s0 * D2 + f];
    unsigned short a1 = h2p[(size_t)s1 * D2 + f];
    unsigned short a2 = h2p[(size_t)s2 * D2 + f];
    unsigned short a3 = h2p[(size_t)s3 * D2 + f];
    acc += bf2f(a0); acc += bf2f(a1); acc += bf2f(a2); acc += bf2f(a3);
  }
  for (; j < cnt; j += 2) acc += bf2f(h2p[(size_t)ell[base + j] * D2 + f]);
  acc += __shfl_down(acc, 32, 64);  // fold upper half into lower
  if (h == 0) {
    out[(size_t)d * D2 + f] = fmaf(node_dinv(deg, d), acc, b2[f]);
  }
}

extern "C" void kernel_launch(void* const* d_in, const int* in_sizes, int n_in,
                              void* d_out, int out_size, void* d_ws, size_t ws_size,
                              hipStream_t stream) {
  const float* x  = (const float*)d_in[0];
  const int*   ei = (const int*)d_in[1];
  const float* W1 = (const float*)d_in[2];
  const float* b1 = (const float*)d_in[3];
  const float* W2 = (const float*)d_in[4];
  const float* b2 = (const float*)d_in[5];
  const int N = in_sizes[0] / DIN;   // 100000
  const int E = in_sizes[1] / 2;     // 1600000
  const int NBK = (N + 255) >> 8;    // 391 buckets of 256 nodes
  const int* src = ei;
  const int* dst = ei + E;
  float* out = (float*)d_out;

  char* ws = (char*)d_ws;
  size_t off = 0;
  auto alloc = [&](size_t bytes) -> char* {
    char* p = ws + off;
    off += (bytes + 255) / 256 * 256;
    return p;
  };
  unsigned short* h1p = (unsigned short*)alloc((size_t)N * D1 * 2);  // bf16; h2p aliases
  float*          h1d = (float*)alloc((size_t)N * D1 * 4);           // fp32; binned aliases
  int*            ell = (int*)alloc((size_t)N * MAXDEG * 4);
  int*            deg = (int*)alloc((size_t)N * 4);
  int*         cursor = (int*)alloc((size_t)NBK * 4);
  unsigned short* h2p = h1p;          // alias: h1p dead after agg1
  uint2*       binned = (uint2*)h1d;  // alias: binned dead before agg1 writes h1d
  // binned needs NBK*BCAP*8 = 14.4 MB <= h1d's 25.6 MB ✓
  (void)ws_size; (void)n_in; (void)out_size;

  hipMemsetAsync(cursor, 0, (size_t)NBK * 4, stream);

  bin_kernel<<<(E + CBLK - 1) / CBLK, 256, 0, stream>>>(src, dst, cursor, binned, E, NBK);
  ellbuild_kernel<<<NBK, 256, 0, stream>>>(binned, cursor, deg, ell, N);
  gemm1_kernel<<<(N + 63) / 64, 256, 0, stream>>>(x, W1, deg, h1p, N);
  agg1_kernel<<<N / 4, 256, 0, stream>>>(deg, ell, h1p, b1, h1d, N);
  gemm2_kernel<<<(N + 127) / 128, 256, 0, stream>>>(h1d, W2, deg, h2p, N);
  agg2_kernel<<<N / 4, 256, 0, stream>>>(deg, ell, h2p, b2, out, N);
}